// Round 5
// baseline (257.956 us; speedup 1.0000x reference)
//
#include <hip/hip_runtime.h>
#include <math.h>

#define BLOCK 256
#define EPT   2
#define EPB   (BLOCK * EPT)      // 512 elements per block

__device__ __forceinline__ float frcp(float x)   { return __builtin_amdgcn_rcpf(x); }
__device__ __forceinline__ float frsq(float x)   { return __builtin_amdgcn_rsqf(x); }
__device__ __forceinline__ float fsqrt_r(float x){ return __builtin_amdgcn_sqrtf(x); }

// ---- 2-wide value/mask types: every op is an adjacent independent pair, so
// the scheduler gets ILP=2 on the dependency chain no matter how it orders. ----
struct v2f { float x, y; };
struct m2  { bool  x, y; };

__device__ __forceinline__ v2f mk2(float v)          { return {v, v}; }
__device__ __forceinline__ v2f operator+(v2f a, v2f b){ return {a.x+b.x, a.y+b.y}; }
__device__ __forceinline__ v2f operator-(v2f a, v2f b){ return {a.x-b.x, a.y-b.y}; }
__device__ __forceinline__ v2f operator*(v2f a, v2f b){ return {a.x*b.x, a.y*b.y}; }
__device__ __forceinline__ v2f operator-(v2f a)       { return {-a.x, -a.y}; }
__device__ __forceinline__ v2f fma2(v2f a, v2f b, v2f c){ return {fmaf(a.x,b.x,c.x), fmaf(a.y,b.y,c.y)}; }
__device__ __forceinline__ v2f max2(v2f a, v2f b)    { return {fmaxf(a.x,b.x), fmaxf(a.y,b.y)}; }
__device__ __forceinline__ v2f min2(v2f a, v2f b)    { return {fminf(a.x,b.x), fminf(a.y,b.y)}; }
__device__ __forceinline__ v2f abs2(v2f a)           { return {fabsf(a.x), fabsf(a.y)}; }
__device__ __forceinline__ v2f rcp2(v2f a)           { return {frcp(a.x), frcp(a.y)}; }
__device__ __forceinline__ v2f rsq2(v2f a)           { return {frsq(a.x), frsq(a.y)}; }
__device__ __forceinline__ v2f sqrt2v(v2f a)         { return {fsqrt_r(a.x), fsqrt_r(a.y)}; }
__device__ __forceinline__ v2f log2v(v2f a)          { return {__logf(a.x), __logf(a.y)}; }
__device__ __forceinline__ v2f exp2v(v2f a)          { return {__expf(a.x), __expf(a.y)}; }
__device__ __forceinline__ v2f cos2v(v2f a)          { return {__cosf(a.x), __cosf(a.y)}; }
__device__ __forceinline__ v2f csign2(v2f a, v2f s)  { return {copysignf(a.x,s.x), copysignf(a.y,s.y)}; }
__device__ __forceinline__ m2  lt2(v2f a, v2f b)     { return {a.x<b.x, a.y<b.y}; }
__device__ __forceinline__ m2  gt2(v2f a, v2f b)     { return {a.x>b.x, a.y>b.y}; }
__device__ __forceinline__ m2  le2(v2f a, v2f b)     { return {a.x<=b.x, a.y<=b.y}; }
__device__ __forceinline__ m2  and2(m2 a, m2 b)      { return {a.x&&b.x, a.y&&b.y}; }
__device__ __forceinline__ m2  or2(m2 a, m2 b)       { return {a.x||b.x, a.y||b.y}; }
__device__ __forceinline__ m2  not2(m2 a)            { return {!a.x, !a.y}; }
__device__ __forceinline__ v2f sel2(m2 m, v2f a, v2f b){ return {m.x?a.x:b.x, m.y?a.y:b.y}; }

// Hastings acos, 2-wide (abs err ~6.8e-5 rad; sigma recovered variationally).
__device__ __forceinline__ v2f acos2(v2f v) {
    v2f ax = abs2(v);
    v2f p = fma2(ax, mk2(-0.0187293f), mk2(0.0742610f));
    p = fma2(ax, p, mk2(-0.2121144f));
    p = fma2(ax, p, mk2(1.5707288f));
    v2f r = sqrt2v(max2(mk2(1.0f)-ax, mk2(0.0f))) * p;
    return sel2(lt2(v, mk2(0.0f)), mk2(3.14159265358979f)-r, r);
}

// Largest-norm cross product among the three row pairs of a symmetric 3x3 (2-wide).
__device__ __forceinline__ void best_cross2(
    v2f r0x, v2f r0y, v2f r0z,
    v2f r1x, v2f r1y, v2f r1z,
    v2f r2x, v2f r2y, v2f r2z,
    v2f& bx, v2f& by, v2f& bz, v2f& bn)
{
    v2f c0x = fma2(r0y,r1z, -(r0z*r1y));
    v2f c0y = fma2(r0z,r1x, -(r0x*r1z));
    v2f c0z = fma2(r0x,r1y, -(r0y*r1x));
    v2f c1x = fma2(r0y,r2z, -(r0z*r2y));
    v2f c1y = fma2(r0z,r2x, -(r0x*r2z));
    v2f c1z = fma2(r0x,r2y, -(r0y*r2x));
    v2f c2x = fma2(r1y,r2z, -(r1z*r2y));
    v2f c2y = fma2(r1z,r2x, -(r1x*r2z));
    v2f c2z = fma2(r1x,r2y, -(r1y*r2x));
    v2f n0 = fma2(c0x,c0x, fma2(c0y,c0y, c0z*c0z));
    v2f n1 = fma2(c1x,c1x, fma2(c1y,c1y, c1z*c1z));
    v2f n2 = fma2(c2x,c2x, fma2(c2y,c2y, c2z*c2z));
    m2 b1 = gt2(n1, n0);
    v2f sx = sel2(b1,c1x,c0x), sy = sel2(b1,c1y,c0y), sz = sel2(b1,c1z,c0z);
    v2f sn = sel2(b1,n1,n0);
    m2 b2m = gt2(n2, sn);
    bx = sel2(b2m,c2x,sx); by = sel2(b2m,c2y,sy); bz = sel2(b2m,c2z,sz);
    bn = sel2(b2m,n2,sn);
}

// Closed-form 3x3 SVD + Drucker-Prager return mapping, two elements zipped.
// Per-element expression tree identical to R2-R4 (absmax canary 0.06973267).
__device__ __forceinline__ void dp_solve2(
    v2f a00, v2f a01, v2f a02,
    v2f a10, v2f a11, v2f a12,
    v2f a20, v2f a21, v2f a22,
    float coh, float ratio,
    v2f& r00, v2f& r01, v2f& r02,
    v2f& r10, v2f& r11, v2f& r12,
    v2f& r20, v2f& r21, v2f& r22)
{
    // ---- Gram matrix S = A^T A ----
    v2f s00 = fma2(a00,a00, fma2(a10,a10, a20*a20));
    v2f s11 = fma2(a01,a01, fma2(a11,a11, a21*a21));
    v2f s22 = fma2(a02,a02, fma2(a12,a12, a22*a22));
    v2f s01 = fma2(a00,a01, fma2(a10,a11, a20*a21));
    v2f s02 = fma2(a00,a02, fma2(a10,a12, a20*a22));
    v2f s12 = fma2(a01,a02, fma2(a11,a12, a21*a22));

    // ---- closed-form eigenvalues (trigonometric cubic) ----
    v2f q   = (s00 + s11 + s22) * mk2(1.0f/3.0f);
    v2f b00 = s00 - q, b11 = s11 - q, b22 = s22 - q;
    v2f offsq = fma2(s01,s01, fma2(s02,s02, s12*s12));
    v2f p2  = fma2(b00,b00, fma2(b11,b11, fma2(b22,b22, mk2(2.0f)*offsq)));
    v2f pp  = sqrt2v(p2 * mk2(1.0f/6.0f));
    v2f pinv = rcp2(max2(pp, mk2(1e-10f)));     // clamp: pinv^3 <= 1e30, no Inf
    v2f det = b00*fma2(b11,b22, -(s12*s12))
            - s01*fma2(s01,b22, -(s12*s02))
            + s02*fma2(s01,s12, -(b11*s02));
    v2f rdet = mk2(0.5f)*det*pinv*pinv*pinv;
    rdet = min2(max2(rdet, mk2(-1.0f)), mk2(1.0f));
    v2f phi  = acos2(rdet) * mk2(1.0f/3.0f);            // in [0, pi/3]
    v2f lam0 = fma2(mk2(2.0f)*pp, cos2v(phi), q);                            // largest
    v2f lam2 = fma2(mk2(2.0f)*pp, cos2v(phi + mk2(2.0943951023931953f)), q); // smallest

    // ---- v0: null direction of (S - lam0 I) ----
    v2f bx, by, bz, bn;
    best_cross2(s00-lam0, s01, s02,
                s01, s11-lam0, s12,
                s02, s12, s22-lam0, bx, by, bz, bn);
    m2 ok0 = gt2(bn, mk2(1e-24f));
    v2f ir0 = rsq2(max2(bn, mk2(1e-30f)));
    v2f v00 = sel2(ok0, bx*ir0, mk2(1.0f));
    v2f v10 = sel2(ok0, by*ir0, mk2(0.0f));
    v2f v20 = sel2(ok0, bz*ir0, mk2(0.0f));

    // ---- v2: null direction of (S - lam2 I), orthogonalized against v0 ----
    best_cross2(s00-lam2, s01, s02,
                s01, s11-lam2, s12,
                s02, s12, s22-lam2, bx, by, bz, bn);
    v2f axv = abs2(v00), ayv = abs2(v10), azv = abs2(v20);
    m2 xm = and2(le2(axv,ayv), le2(axv,azv));
    m2 ym = and2(not2(xm), le2(ayv,azv));
    m2 xym = or2(xm, ym);
    v2f ex = sel2(xm, mk2(1.0f), mk2(0.0f));
    v2f ey = sel2(ym, mk2(1.0f), mk2(0.0f));
    v2f ez = sel2(xym, mk2(0.0f), mk2(1.0f));
    v2f fx = fma2(v10,ez, -(v20*ey));          // fallback perp to v0
    v2f fy = fma2(v20,ex, -(v00*ez));
    v2f fz = fma2(v00,ey, -(v10*ex));
    m2 ok2m = gt2(bn, mk2(1e-24f));
    v2f wx = sel2(ok2m, bx, fx), wy = sel2(ok2m, by, fy), wz = sel2(ok2m, bz, fz);
    v2f dp = fma2(wx,v00, fma2(wy,v10, wz*v20));   // Gram-Schmidt vs v0
    wx = fma2(-dp, v00, wx); wy = fma2(-dp, v10, wy); wz = fma2(-dp, v20, wz);
    v2f wn = fma2(wx,wx, fma2(wy,wy, wz*wz));
    m2 okw = gt2(wn, mk2(1e-24f));
    wx = sel2(okw, wx, fx); wy = sel2(okw, wy, fy); wz = sel2(okw, wz, fz);
    wn = sel2(okw, wn, fma2(fx,fx, fma2(fy,fy, fz*fz)));
    v2f irw = rsq2(max2(wn, mk2(1e-30f)));
    v2f v02 = wx*irw, v12 = wy*irw, v22 = wz*irw;
    // v1 = v2 x v0 -> (v0,v1,v2) right-handed
    v2f v01 = fma2(v12,v20, -(v22*v10));
    v2f v11 = fma2(v22,v00, -(v02*v20));
    v2f v21 = fma2(v02,v10, -(v12*v00));

    // ---- U columns: u_i = normalize(A v_i); sigma_i^2 = |A v_i|^2 ----
    v2f q0 = fma2(a00,v00, fma2(a01,v10, a02*v20));
    v2f q1 = fma2(a10,v00, fma2(a11,v10, a12*v20));
    v2f q2 = fma2(a20,v00, fma2(a21,v10, a22*v20));
    v2f m0 = fma2(q0,q0, fma2(q1,q1, q2*q2));
    v2f i0 = rsq2(max2(m0, mk2(1e-30f)));
    v2f u00 = q0*i0, u10 = q1*i0, u20 = q2*i0;

    q0 = fma2(a00,v01, fma2(a01,v11, a02*v21));
    q1 = fma2(a10,v01, fma2(a11,v11, a12*v21));
    q2 = fma2(a20,v01, fma2(a21,v11, a22*v21));
    v2f m1 = fma2(q0,q0, fma2(q1,q1, q2*q2));
    v2f i1 = rsq2(max2(m1, mk2(1e-30f)));
    v2f u01 = q0*i1, u11 = q1*i1, u21 = q2*i1;

    v2f u02 = fma2(u10,u21, -(u20*u11));       // u2 = u0 x u1
    v2f u12 = fma2(u20,u01, -(u00*u21));
    v2f u22 = fma2(u00,u11, -(u10*u01));

    // signed third singular term: s2 = u2^T A v2
    v2f w0 = fma2(a00,v02, fma2(a01,v12, a02*v22));
    v2f w1 = fma2(a10,v02, fma2(a11,v12, a12*v22));
    v2f w2 = fma2(a20,v02, fma2(a21,v12, a22*v22));
    v2f s2 = fma2(u02,w0, fma2(u12,w1, u22*w2));

    // ---- Drucker-Prager return mapping on log strains ----
    v2f e0 = mk2(0.5f)*log2v(max2(m0, mk2(0.0025f)));
    v2f e1 = mk2(0.5f)*log2v(max2(m1, mk2(0.0025f)));
    v2f e2 = log2v(max2(abs2(s2), mk2(0.05f)));
    v2f tr  = e0 + e1 + e2;
    v2f tr3 = tr * mk2(1.0f/3.0f);
    v2f h0 = e0 - tr3, h1 = e1 - tr3, h2 = e2 - tr3;
    v2f hn = sqrt2v(fma2(h0,h0, fma2(h1,h1, h2*h2)));
    hn = max2(hn, mk2(1e-10f));
    v2f st = tr - mk2(coh*3.0f);
    v2f dg = hn + mk2(ratio)*st;
    v2f sc = max2(dg, mk2(0.0f)) * rcp2(hn);
    m2 yield = lt2(st, mk2(0.0f));
    v2f ec0 = sel2(yield, fma2(-sc, h0, e0), mk2(coh));
    v2f ec1 = sel2(yield, fma2(-sc, h1, e1), mk2(coh));
    v2f ec2 = sel2(yield, fma2(-sc, h2, e2), mk2(coh));
    v2f g0 = exp2v(ec0);
    v2f g1 = exp2v(ec1);
    v2f g2 = csign2(exp2v(ec2), s2);

    // ---- F_corrected = sum_k g_k * u_k * v_k^T ----
    v2f w00 = u00*g0, w01 = u01*g1, w02 = u02*g2;
    v2f w10 = u10*g0, w11 = u11*g1, w12 = u12*g2;
    v2f w20 = u20*g0, w21 = u21*g1, w22 = u22*g2;
    r00 = fma2(w00,v00, fma2(w01,v01, w02*v02));
    r01 = fma2(w00,v10, fma2(w01,v11, w02*v12));
    r02 = fma2(w00,v20, fma2(w01,v21, w02*v22));
    r10 = fma2(w10,v00, fma2(w11,v01, w12*v02));
    r11 = fma2(w10,v10, fma2(w11,v11, w12*v12));
    r12 = fma2(w10,v20, fma2(w11,v21, w12*v22));
    r20 = fma2(w20,v00, fma2(w21,v01, w22*v02));
    r21 = fma2(w20,v10, fma2(w21,v11, w22*v12));
    r22 = fma2(w20,v20, fma2(w21,v21, w22*v22));
}

// Pure map kernel, 2 elements/thread zipped at expression level.
// Thread t handles records base+t and base+BLOCK+t: per wave, two contiguous
// 2304 B spans -> fully coalesced after SILoadStoreOptimizer merging.
__global__ __launch_bounds__(BLOCK, 4) void dp_kernel(
    const float* __restrict__ F,
    const float* __restrict__ p_yml,
    const float* __restrict__ p_nu,
    const float* __restrict__ p_fa,
    const float* __restrict__ p_coh,
    float* __restrict__ out,
    int n_elem)
{
    const int t    = threadIdx.x;
    const int base = (int)blockIdx.x * EPB;
    const int idxA = base + t;
    const int idxB = base + BLOCK + t;
    const bool vA = idxA < n_elem;
    const bool vB = idxB < n_elem;
    const float* pA = F + (vA ? idxA : 0) * 9;
    const float* pB = F + (vB ? idxB : 0) * 9;

    v2f a00 = {pA[0], pB[0]}, a01 = {pA[1], pB[1]}, a02 = {pA[2], pB[2]};
    v2f a10 = {pA[3], pB[3]}, a11 = {pA[4], pB[4]}, a12 = {pA[5], pB[5]};
    v2f a20 = {pA[6], pB[6]}, a21 = {pA[7], pB[7]}, a22 = {pA[8], pB[8]};

    // ---- material params (uniform) ----
    const float yml = p_yml[0];
    const float nu  = p_nu[0];
    const float fa  = p_fa[0];
    const float coh = p_coh[0];
    const float E     = __expf(yml);
    const float sphi  = __sinf(fa * 0.017453292519943295f);
    const float alpha = 1.632993161855452f * sphi * frcp(3.0f - sphi);
    const float mu    = E * 0.5f * frcp(1.0f + nu);
    const float la    = E * nu * frcp((1.0f + nu) * (1.0f - 2.0f * nu));
    const float ratio = (3.0f * la + 2.0f * mu) * frcp(2.0f * mu) * alpha;

    v2f r00,r01,r02,r10,r11,r12,r20,r21,r22;
    dp_solve2(a00,a01,a02,a10,a11,a12,a20,a21,a22, coh, ratio,
              r00,r01,r02,r10,r11,r12,r20,r21,r22);

    if (vA) {
        float* o = out + idxA * 9;
        o[0]=r00.x; o[1]=r01.x; o[2]=r02.x;
        o[3]=r10.x; o[4]=r11.x; o[5]=r12.x;
        o[6]=r20.x; o[7]=r21.x; o[8]=r22.x;
    }
    if (vB) {
        float* o = out + idxB * 9;
        o[0]=r00.y; o[1]=r01.y; o[2]=r02.y;
        o[3]=r10.y; o[4]=r11.y; o[5]=r12.y;
        o[6]=r20.y; o[7]=r21.y; o[8]=r22.y;
    }
}

extern "C" void kernel_launch(void* const* d_in, const int* in_sizes, int n_in,
                              void* d_out, int out_size, void* d_ws, size_t ws_size,
                              hipStream_t stream) {
    const float* F = (const float*)d_in[0];
    const int n_elem = in_sizes[0] / 9;
    const int grid = (n_elem + EPB - 1) / EPB;
    dp_kernel<<<grid, BLOCK, 0, stream>>>(
        F,
        (const float*)d_in[1], (const float*)d_in[2],
        (const float*)d_in[3], (const float*)d_in[4],
        (float*)d_out, n_elem);
}